// Round 13
// baseline (76.433 us; speedup 1.0000x reference)
//
#include <hip/hip_runtime.h>
#include <hip/hip_bf16.h>

// Problem constants
#define BDIM 1024
#define NCOL 1152      // 9 heads * 64 * 2 (q,k)
#define HEADS 9
#define HID 64
#define SLEN 512
#define BATCH 16

typedef __attribute__((ext_vector_type(8))) short bf16x8;
typedef __attribute__((ext_vector_type(8))) unsigned short u16x8;
typedef __attribute__((ext_vector_type(4))) float f32x4;
typedef __attribute__((ext_vector_type(4))) unsigned short u16x4;

static __device__ __forceinline__ unsigned short f2bf(float f) {
    union { float f; unsigned int u; } x; x.f = f;
    unsigned int u = x.u;
    unsigned int r = (u + 0x7fffu + ((u >> 16) & 1u)) >> 16;
    return (unsigned short)r;
}

// packed f32x2 -> bf16x2 (RNE) - single HW instruction, bit-identical to f2bf
static __device__ __forceinline__ unsigned int pk2bf(float lo, float hi) {
    unsigned int r;
    asm("v_cvt_pk_bf16_f32 %0, %1, %2" : "=v"(r) : "v"(lo), "v"(hi));
    return r;
}

#define GLOAD_LDS16(g, l)                                                     \
    __builtin_amdgcn_global_load_lds(                                         \
        (const __attribute__((address_space(1))) unsigned int*)(g),           \
        (__attribute__((address_space(3))) unsigned int*)(l), 16, 0, 0)

// ---------------------------------------------------------------------------
// Prep kernel: blocks [0,1152): W [1024][1152] f32 -> Wt [1152][1024] bf16
//              blocks [1152,1216): RoPE table sctab[512][32] of {sin,cos}
// (A-conversion eliminated: proj reg-stages hidden f32 directly, T14)
// ---------------------------------------------------------------------------
__global__ __launch_bounds__(256) void prep_kernel(const float* __restrict__ W,
                                                   unsigned short* __restrict__ Wt,
                                                   float* __restrict__ sctab) {
    __shared__ float tile[32][33];
    const int b = blockIdx.x;
    if (b < 1152) {
        const int tx = threadIdx.x & 31;
        const int ty = threadIdx.x >> 5;      // 0..7
        const int nb = (b % 36) * 32;         // over NCOL
        const int kb = (b / 36) * 32;         // over BDIM
#pragma unroll
        for (int i = 0; i < 4; ++i) {
            int k = kb + ty + i * 8;
            tile[ty + i * 8][tx] = W[(size_t)k * NCOL + nb + tx];
        }
        __syncthreads();
#pragma unroll
        for (int i = 0; i < 4; ++i) {
            int n = nb + ty + i * 8;
            Wt[(size_t)n * BDIM + kb + tx] = f2bf(tile[tx][ty + i * 8]);
        }
    } else {
        int idx = (b - 1152) * 256 + threadIdx.x;   // 0..16383
        int s = idx >> 5, j = idx & 31;
        float inv = powf(10000.0f, -(float)(2 * j) / (float)HID);
        float ang = (float)s * inv;
        sctab[idx * 2]     = sinf(ang);
        sctab[idx * 2 + 1] = cosf(ang);
    }
}

// ---------------------------------------------------------------------------
// Projection GEMM (8192x1024 f32-A @ 1024x1152 bf16-B) + bias + RoPE
// -> qk bf16 [16][9][2][512][64]
// BM=256 x BN=144, grid 32x8 = 256 blocks = 1/CU, one round. 8 waves, BK=64.
// A: T14 reg-staged f32, COMPILER-MANAGED loads. Issue in ph0 for it+1;
//    cvt_pk + swizzled ds_write_b64 at end of iter (write-late). 2-buf As.
// B: R8's PROVEN geometry - waves 0-5, 24 rows each (3 gloads), 144 total.
//    (R10/R12 NaN root cause: wrong 40/32-row split wrote 208 rows OOB.)
//    3-buffer 2-deep global_load_lds, source-side XOR-8 swizzle (rule #21).
// vmcnt audit (bcnt=3): end-of-iter tail = B(it+1)x3, A(it+1)x8, B(it+2)x3;
//    compiler's av-wait = vmcnt(3) drains A(it+1)+B(it+1), keeps B(it+2).
// T5 setprio around MFMA clusters; sched_barrier fences per rule #18.
// LDS: A 2x32KB + B 3x18KB = 118 KB. MFMA operand-swapped (acc along d).
// ---------------------------------------------------------------------------
__global__ __launch_bounds__(512) void proj_rope_kernel(
    const float* __restrict__ hidden,        // [8192][1024] f32
    const unsigned short* __restrict__ Wt,   // [1152][1024] bf16
    const float* __restrict__ bias,          // [1152]
    const float4* __restrict__ sctab4,       // [512][16] {s,c,s,c}
    unsigned short* __restrict__ qk)         // [16][9][2][512][64] bf16
{
    __shared__ __attribute__((aligned(16))) unsigned short As[2][256 * 64]; // 64 KB
    __shared__ __attribute__((aligned(16))) unsigned short Bs[3][144 * 64]; // 54 KB

    const int t = threadIdx.x;
    const int m0 = blockIdx.x * 256;
    const int n0 = blockIdx.y * 144;
    const int wid = t >> 6, lane = t & 63;
    const int lrow = lane & 15;
    const int lk = lane >> 4;                 // 0..3

    // --- A reg-staging: lane (r8=lane>>4, q=lane&15) loads row wid*32+i*4+r8,
    //     f32 cols q*4..q*4+3 of the current K-slab (i=0..7 -> 32 rows/wave).
    const int r8 = lane >> 4;                 // 0..3
    const int q  = lane & 15;                 // 0..15
    const float* aBase = hidden + (size_t)(m0 + wid * 32 + r8) * BDIM + q * 4;

    // --- B staging (R8 geometry): 8 lanes x 16B per 128B row; 8 rows/gload.
    const int rowoff = lane >> 3;                          // 0..7
    const int sslot = (lane & 7) ^ rowoff;                 // source 16B slot
    const unsigned short* gB = Wt + (size_t)(n0 + wid * 24 + rowoff) * BDIM + sslot * 8;
    const int lB = wid * 1536;                // elems: wave chunk in Bs (wid<6)
    const bool hasB = (wid < 6);

#define STAGE_B(buf, k0)                                                      \
    do {                                                                      \
        GLOAD_LDS16(gB + (k0),             &Bs[buf][lB]);                     \
        GLOAD_LDS16(gB + (k0) + 8 * BDIM,  &Bs[buf][lB + 512]);               \
        GLOAD_LDS16(gB + (k0) + 16 * BDIM, &Bs[buf][lB + 1024]);              \
    } while (0)

// compiler-managed f32 loads (LLVM inserts the counted vmcnt before use)
#define LOAD_A(k0f)                                                           \
    do {                                                                      \
        _Pragma("unroll")                                                     \
        for (int i = 0; i < 8; ++i)                                           \
            av[i] = *reinterpret_cast<const f32x4*>(aBase + (k0f) + i * 4 * BDIM); \
    } while (0)

// cvt + swizzled ds_write_b64: source slot s -> physical slot s^(row&7)
#define CVT_WRITE_A(buf)                                                      \
    do {                                                                      \
        _Pragma("unroll")                                                     \
        for (int i = 0; i < 8; ++i) {                                         \
            unsigned int lo_ = pk2bf(av[i][0], av[i][1]);                     \
            unsigned int hi_ = pk2bf(av[i][2], av[i][3]);                     \
            int rl_ = wid * 32 + i * 4 + r8;                                  \
            int bo_ = (((q >> 1) ^ (rl_ & 7)) << 4) | ((q & 1) << 3);         \
            *reinterpret_cast<uint2*>((char*)As[buf] + rl_ * 128 + bo_) =     \
                make_uint2(lo_, hi_);                                         \
        }                                                                     \
    } while (0)

    // --- fragment read swizzle: slot key = row&7 = lrow&7
    const int rkey = lrow & 7;

    f32x4 acc[9][2] = {};                     // [ni][mi], regs along n/d
    f32x4 av[8];                              // in-flight A tile (32 VGPR)

    // ---- prologue: A(0) reg-loads; B(0),B(1) gloads; A(0) -> LDS
    LOAD_A(0);
    if (hasB) { STAGE_B(0, 0); STAGE_B(1, 64); }
    __builtin_amdgcn_sched_barrier(0);
    CVT_WRITE_A(0);                           // compiler waits av here
    asm volatile("s_waitcnt lgkmcnt(0)" ::: "memory");
    if (hasB) asm volatile("s_waitcnt vmcnt(3)" ::: "memory");  // drain B(0)
    __builtin_amdgcn_sched_barrier(0);

    for (int it = 0; it < 16; ++it) {
        __builtin_amdgcn_s_barrier();
        __builtin_amdgcn_sched_barrier(0);

        const char* Ac = (const char*)As[it & 1];
        const char* Bc = (const char*)Bs[it % 3];

        // ---- phase 0: kk=0 frag reads + A(it+1) reg-issue + MFMA
        {
            const int fslot = (lk ^ rkey) << 4;
            bf16x8 af[2], bfr[9];
#pragma unroll
            for (int mi = 0; mi < 2; ++mi)
                af[mi] = *reinterpret_cast<const bf16x8*>(
                    Ac + (wid * 32 + mi * 16 + lrow) * 128 + fslot);
#pragma unroll
            for (int ni = 0; ni < 9; ++ni)
                bfr[ni] = *reinterpret_cast<const bf16x8*>(
                    Bc + (ni * 16 + lrow) * 128 + fslot);
            if (it < 15) LOAD_A((it + 1) * 64);
            __builtin_amdgcn_sched_barrier(0);
            asm volatile("s_waitcnt lgkmcnt(0)" ::: "memory");
            __builtin_amdgcn_sched_barrier(0);
            __builtin_amdgcn_s_setprio(1);
#pragma unroll
            for (int ni = 0; ni < 9; ++ni)
#pragma unroll
                for (int mi = 0; mi < 2; ++mi)
                    acc[ni][mi] = __builtin_amdgcn_mfma_f32_16x16x32_bf16(
                        bfr[ni], af[mi], acc[ni][mi], 0, 0, 0);
            __builtin_amdgcn_s_setprio(0);
        }
        __builtin_amdgcn_s_barrier();
        __builtin_amdgcn_sched_barrier(0);

        // ---- phase 1: kk=1 frag reads + B(it+2) gload-issue + MFMA
        {
            const int fslot = ((4 + lk) ^ rkey) << 4;
            bf16x8 af[2], bfr[9];
#pragma unroll
            for (int mi = 0; mi < 2; ++mi)
                af[mi] = *reinterpret_cast<const bf16x8*>(
                    Ac + (wid * 32 + mi * 16 + lrow) * 128 + fslot);
#pragma unroll
            for (int ni = 0; ni < 9; ++ni)
                bfr[ni] = *reinterpret_cast<const bf16x8*>(
                    Bc + (ni * 16 + lrow) * 128 + fslot);
            if (it < 14 && hasB) STAGE_B((it + 2) % 3, (it + 2) * 64);
            __builtin_amdgcn_sched_barrier(0);
            asm volatile("s_waitcnt lgkmcnt(0)" ::: "memory");
            __builtin_amdgcn_sched_barrier(0);
            __builtin_amdgcn_s_setprio(1);
#pragma unroll
            for (int ni = 0; ni < 9; ++ni)
#pragma unroll
                for (int mi = 0; mi < 2; ++mi)
                    acc[ni][mi] = __builtin_amdgcn_mfma_f32_16x16x32_bf16(
                        bfr[ni], af[mi], acc[ni][mi], 0, 0, 0);
            __builtin_amdgcn_s_setprio(0);
        }

        // ---- end of iter: cvt A(it+1) (compiler drains A(it+1)+B(it+1),
        // keeps B(it+2) in flight), swizzled ds_write to As[(it+1)&1]
        if (it < 15) {
            CVT_WRITE_A((it + 1) & 1);
            asm volatile("s_waitcnt lgkmcnt(0)" ::: "memory");
            __builtin_amdgcn_sched_barrier(0);
        }
    }
#undef STAGE_B
#undef LOAD_A
#undef CVT_WRITE_A

    // epilogue: bias + RoPE (in-register pairs) + ushort4 stores
    const float4* bias4 = (const float4*)bias;
#pragma unroll
    for (int ni = 0; ni < 9; ++ni) {
        int cb = n0 + ni * 16 + lk * 4;              // 4 consecutive columns
        float4 bv = bias4[cb >> 2];
        int h = cb >> 7;
        int qki = (cb >> 6) & 1;
        int d0 = cb & 63;                            // multiple of 4
#pragma unroll
        for (int mi = 0; mi < 2; ++mi) {
            int m = m0 + wid * 32 + mi * 16 + lrow;
            int bi = m >> 9, s = m & 511;
            float4 sc = sctab4[s * 16 + (d0 >> 2)];  // {sin j, cos j, sin j+1, cos j+1}
            f32x4 a = acc[ni][mi];
            float v0 = a[0] + bv.x, v1 = a[1] + bv.y;
            float v2 = a[2] + bv.z, v3 = a[3] + bv.w;
            u16x4 p;
            p[0] = f2bf(v0 * sc.y - v1 * sc.x);
            p[1] = f2bf(v1 * sc.y + v0 * sc.x);
            p[2] = f2bf(v2 * sc.w - v3 * sc.z);
            p[3] = f2bf(v3 * sc.w + v2 * sc.z);
            *reinterpret_cast<u16x4*>(
                qk + ((((size_t)bi * HEADS + h) * 2 + qki) * SLEN + s) * HID + d0) = p;
        }
    }
}

// ---------------------------------------------------------------------------
// logits[b,h,m,n] = (q.k * pad - (1-pad)*1e12) / 8
// per (b,h): 512x64 @ 64x512; grid (4,4,144), 128x128 tiles.
// MFMA operand-swapped. LDS-transposed epilogue (R11): per mi-chunk, waves
// write masked f32x4 into a [32][136] f32 tile, then 256 threads store
// contiguous 512B row-chunks (fully coalesced).
// ---------------------------------------------------------------------------
__global__ __launch_bounds__(256) void logits_kernel(
    const unsigned short* __restrict__ qkbuf,  // [16][9][2][512][64] bf16
    const float* __restrict__ mask,            // [16][512]
    float* __restrict__ out)                   // [16][9][512][512]
{
    __shared__ __attribute__((aligned(16))) unsigned short Qs[128 * 72];
    __shared__ __attribute__((aligned(16))) unsigned short Ks[128 * 72];

    const int t = threadIdx.x;
    const int bz = blockIdx.z;                 // b*9 + h
    const int bi = bz / 9;
    const int m0 = blockIdx.x * 128, n0 = blockIdx.y * 128;

    const unsigned short* Qg = qkbuf + ((size_t)bz * 2 + 0) * SLEN * HID + (size_t)m0 * HID;
    const unsigned short* Kg = qkbuf + ((size_t)bz * 2 + 1) * SLEN * HID + (size_t)n0 * HID;

#pragma unroll
    for (int i = 0; i < 4; ++i) {
        int e = t + i * 256;                   // 0..1023
        int row = e >> 3, c = e & 7;           // 8 x 16B per 64-elem row
        *reinterpret_cast<uint4*>(&Qs[row * 72 + c * 8]) =
            *reinterpret_cast<const uint4*>(Qg + (size_t)row * HID + c * 8);
        *reinterpret_cast<uint4*>(&Ks[row * 72 + c * 8]) =
            *reinterpret_cast<const uint4*>(Kg + (size_t)row * HID + c * 8);
    }
    __syncthreads();

    const int wid = t >> 6, lane = t & 63;
    const int wr = wid >> 1, wc = wid & 1;
    const int lrow = lane & 15;
    const int lk = lane >> 4;

    f32x4 acc[4][4] = {};                      // [ni][mi]
#pragma unroll
    for (int kk = 0; kk < 2; ++kk) {
        bf16x8 af[4], bfr[4];
#pragma unroll
        for (int mi = 0; mi < 4; ++mi)
            af[mi] = *reinterpret_cast<const bf16x8*>(
                &Qs[(wr * 64 + mi * 16 + lrow) * 72 + kk * 32 + lk * 8]);
#pragma unroll
        for (int ni = 0; ni < 4; ++ni)
            bfr[ni] = *reinterpret_cast<const bf16x8*>(
                &Ks[(wc * 64 + ni * 16 + lrow) * 72 + kk * 32 + lk * 8]);
#pragma unroll
        for (int ni = 0; ni < 4; ++ni)
#pragma unroll
            for (int mi = 0; mi < 4; ++mi)
                acc[ni][mi] = __builtin_amdgcn_mfma_f32_16x16x32_bf16(
                    bfr[ni], af[mi], acc[ni][mi], 0, 0, 0);
    }

    // mask factors per lane (depend only on n -> ni)
    float4 pv[4]; float4 sub[4];
#pragma unroll
    for (int ni = 0; ni < 4; ++ni) {
        int nb = n0 + wc * 64 + ni * 16 + lk * 4;
        pv[ni] = *reinterpret_cast<const float4*>(mask + bi * SLEN + nb);
        sub[ni].x = (1.0f - pv[ni].x) * 1000000000000.0f;
        sub[ni].y = (1.0f - pv[ni].y) * 1000000000000.0f;
        sub[ni].z = (1.0f - pv[ni].z) * 1000000000000.0f;
        sub[ni].w = (1.0f - pv[ni].w) * 1000000000000.0f;
    }

    // LDS-transposed store: chunk = 32 rows (wr bands) x 128 cols, pad 136
    float* tr = reinterpret_cast<float*>(Qs);   // 32*136*4 = 17408 B < 18432 B
    __syncthreads();                            // all Qs/Ks reads complete
#pragma unroll
    for (int mi = 0; mi < 4; ++mi) {
        if (mi) __syncthreads();                // prev chunk fully stored
#pragma unroll
        for (int ni = 0; ni < 4; ++ni) {
            int col = wc * 64 + ni * 16 + lk * 4;    // 0..127 within tile
            f32x4 a = acc[ni][mi];
            f32x4 o;
            o[0] = (a[0] * pv[ni].x - sub[ni].x) * 0.125f;
            o[1] = (a[1] * pv[ni].y - sub[ni].y) * 0.125f;
            o[2] = (a[2] * pv[ni].z - sub[ni].z) * 0.125f;
            o[3] = (a[3] * pv[ni].w - sub[ni].w) * 0.125f;
            *reinterpret_cast<f32x4*>(&tr[(wr * 16 + lrow) * 136 + col]) = o;
        }
        __syncthreads();
        // store 32 rows x 512B contiguous chunks, fully coalesced
#pragma unroll
        for (int j = 0; j < 4; ++j) {
            int idx = t + j * 256;               // 0..1023
            int r_l = idx >> 5, c4 = idx & 31;   // row 0..31, 16B col 0..31
            int m = m0 + (r_l >> 4) * 64 + mi * 16 + (r_l & 15);
            f32x4 v = *reinterpret_cast<const f32x4*>(&tr[r_l * 136 + c4 * 4]);
            *reinterpret_cast<f32x4*>(
                out + ((size_t)bz * SLEN + m) * SLEN + n0 + c4 * 4) = v;
        }
    }
}

// ---------------------------------------------------------------------------
extern "C" void kernel_launch(void* const* d_in, const int* in_sizes, int n_in,
                              void* d_out, int out_size, void* d_ws, size_t ws_size,
                              hipStream_t stream) {
    const float* hidden = (const float*)d_in[0];   // 16*512*1024
    const float* mask   = (const float*)d_in[1];   // 16*512
    const float* W      = (const float*)d_in[2];   // 1024*1152
    const float* bias   = (const float*)d_in[3];   // 1152
    float* out = (float*)d_out;

    char* ws = (char*)d_ws;
    unsigned short* Wt = (unsigned short*)ws;                 // 2,359,296 B
    float* sctab = (float*)(ws + 2359296);                    //   131,072 B
    unsigned short* qk = (unsigned short*)(ws + 2359296 + 131072); // 18,874,368 B

    prep_kernel<<<1216, 256, 0, stream>>>(W, Wt, sctab);
    proj_rope_kernel<<<dim3(32, 8), 512, 0, stream>>>(
        hidden, Wt, bias, (const float4*)sctab, qk);
    logits_kernel<<<dim3(4, 4, BATCH * HEADS), 256, 0, stream>>>(qk, mask, out);
}

// Round 14
// 72.811 us; speedup vs baseline: 1.0497x; 1.0497x over previous
//
#include <hip/hip_runtime.h>
#include <hip/hip_bf16.h>

// Problem constants
#define BDIM 1024
#define NCOL 1152      // 9 heads * 64 * 2 (q,k)
#define HEADS 9
#define HID 64
#define SLEN 512
#define BATCH 16

typedef __attribute__((ext_vector_type(8))) short bf16x8;
typedef __attribute__((ext_vector_type(8))) unsigned short u16x8;
typedef __attribute__((ext_vector_type(4))) float f32x4;
typedef __attribute__((ext_vector_type(4))) unsigned short u16x4;

static __device__ __forceinline__ unsigned short f2bf(float f) {
    union { float f; unsigned int u; } x; x.f = f;
    unsigned int u = x.u;
    unsigned int r = (u + 0x7fffu + ((u >> 16) & 1u)) >> 16;
    return (unsigned short)r;
}

#define GLOAD_LDS16(g, l)                                                     \
    __builtin_amdgcn_global_load_lds(                                         \
        (const __attribute__((address_space(1))) unsigned int*)(g),           \
        (__attribute__((address_space(3))) unsigned int*)(l), 16, 0, 0)

// ---------------------------------------------------------------------------
// Prep kernel (fused):
//   blocks [0,4096):     hidden f32 -> Ab bf16 (2048 elems/block)
//   blocks [4096,5248):  W [1024][1152] f32 -> Wt [1152][1024] bf16
//   blocks [5248,5312):  RoPE table sctab[512][32] of {sin,cos}
// ---------------------------------------------------------------------------
__global__ __launch_bounds__(256) void prep_kernel(const float* __restrict__ hidden,
                                                   const float* __restrict__ W,
                                                   unsigned short* __restrict__ Ab,
                                                   unsigned short* __restrict__ Wt,
                                                   float* __restrict__ sctab) {
    __shared__ float tile[32][33];
    const int b = blockIdx.x;
    if (b < 4096) {
        int i = (b * 256 + threadIdx.x) * 8;
        float4 a = *reinterpret_cast<const float4*>(hidden + i);
        float4 c = *reinterpret_cast<const float4*>(hidden + i + 4);
        u16x8 p;
        p[0] = f2bf(a.x); p[1] = f2bf(a.y); p[2] = f2bf(a.z); p[3] = f2bf(a.w);
        p[4] = f2bf(c.x); p[5] = f2bf(c.y); p[6] = f2bf(c.z); p[7] = f2bf(c.w);
        *reinterpret_cast<u16x8*>(Ab + i) = p;
    } else if (b < 5248) {
        const int bb = b - 4096;
        const int tx = threadIdx.x & 31;
        const int ty = threadIdx.x >> 5;      // 0..7
        const int nb = (bb % 36) * 32;        // over NCOL
        const int kb = (bb / 36) * 32;        // over BDIM
#pragma unroll
        for (int i = 0; i < 4; ++i) {
            int k = kb + ty + i * 8;
            tile[ty + i * 8][tx] = W[(size_t)k * NCOL + nb + tx];
        }
        __syncthreads();
#pragma unroll
        for (int i = 0; i < 4; ++i) {
            int n = nb + ty + i * 8;
            Wt[(size_t)n * BDIM + kb + tx] = f2bf(tile[tx][ty + i * 8]);
        }
    } else {
        int idx = (b - 5248) * 256 + threadIdx.x;   // 0..16383
        int s = idx >> 5, j = idx & 31;
        float inv = powf(10000.0f, -(float)(2 * j) / (float)HID);
        float ang = (float)s * inv;
        sctab[idx * 2]     = sinf(ang);
        sctab[idx * 2 + 1] = cosf(ang);
    }
}

// ---------------------------------------------------------------------------
// Projection GEMM (8192x1024 @ 1024x1152, both bf16) + bias + RoPE
// -> qk bf16 [16][9][2][512][64]
// R8 geometry (proven): BM=256 x BN=144, grid 32x8 = 256 blocks = 1/CU.
// 8 waves, each 32 rows x 144 cols (2x9 frags), BK=64.
// NEW vs R8/R11: the two 18-MFMA phases are FUSED - per iter one barrier,
// one lgkmcnt(0) drain, 22 ds_read_b128 up front, then a 36-MFMA setprio
// cluster. Counted vmcnt unchanged (stage = A4+B3 per hasB-wave).
// XOR-8 swizzle on 16B slots (source-side for gload_lds + swizzled ds_read).
// MFMA operand-swapped: acc regs run along the column (d) dimension.
// ---------------------------------------------------------------------------
__global__ __launch_bounds__(512) void proj_rope_kernel(
    const unsigned short* __restrict__ Ab,   // [8192][1024] bf16
    const unsigned short* __restrict__ Wt,   // [1152][1024] bf16
    const float* __restrict__ bias,          // [1152]
    const float4* __restrict__ sctab4,       // [512][16] {s,c,s,c}
    unsigned short* __restrict__ qk)         // [16][9][2][512][64] bf16
{
    __shared__ __attribute__((aligned(16))) unsigned short As[3][256 * 64]; // 96 KB
    __shared__ __attribute__((aligned(16))) unsigned short Bs[3][144 * 64]; // 54 KB

    const int t = threadIdx.x;
    const int m0 = blockIdx.x * 256;
    const int n0 = blockIdx.y * 144;
    const int wid = t >> 6, lane = t & 63;
    const int lrow = lane & 15;
    const int lk = lane >> 4;                 // 0..3

    const int rowoff = lane >> 3;                          // 0..7
    const int sslot = (lane & 7) ^ rowoff;                 // source 16B slot
    const unsigned short* gA = Ab + (size_t)(m0 + wid * 32 + rowoff) * BDIM + sslot * 8;
    const unsigned short* gB = Wt + (size_t)(n0 + wid * 24 + rowoff) * BDIM + sslot * 8;
    const int lA = wid * 2048;                // elems: wave chunk in As
    const int lB = wid * 1536;                // elems: wave chunk in Bs (wid<6)
    const bool hasB = (wid < 6);

#define STAGE_A(buf, k0)                                                      \
    do {                                                                      \
        GLOAD_LDS16(gA + (k0),             &As[buf][lA]);                     \
        GLOAD_LDS16(gA + (k0) + 8 * BDIM,  &As[buf][lA + 512]);               \
        GLOAD_LDS16(gA + (k0) + 16 * BDIM, &As[buf][lA + 1024]);              \
        GLOAD_LDS16(gA + (k0) + 24 * BDIM, &As[buf][lA + 1536]);              \
    } while (0)
#define STAGE_B(buf, k0)                                                      \
    do {                                                                      \
        GLOAD_LDS16(gB + (k0),             &Bs[buf][lB]);                     \
        GLOAD_LDS16(gB + (k0) + 8 * BDIM,  &Bs[buf][lB + 512]);               \
        GLOAD_LDS16(gB + (k0) + 16 * BDIM, &Bs[buf][lB + 1024]);              \
    } while (0)

    const int rkey = lrow & 7;

    f32x4 acc[9][2] = {};                     // [ni][mi], regs along n/d

    STAGE_A(0, 0);  if (hasB) STAGE_B(0, 0);
    STAGE_A(1, 64); if (hasB) STAGE_B(1, 64);

    int cur = 0;
    for (int it = 0; it < 16; ++it) {
        // counted wait: stage(it) complete, stage(it+1) stays in flight
        if (it < 15) {
            if (hasB) asm volatile("s_waitcnt vmcnt(7)" ::: "memory");
            else      asm volatile("s_waitcnt vmcnt(4)" ::: "memory");
        } else {
            asm volatile("s_waitcnt vmcnt(0)" ::: "memory");
        }
        __builtin_amdgcn_s_barrier();
        __builtin_amdgcn_sched_barrier(0);

        const char* Ac = (const char*)As[cur];
        const char* Bc = (const char*)Bs[cur];
        const int nb2 = (cur + 2 >= 3) ? cur - 1 : cur + 2;   // (it+2)%3

        // ---- fused phase: all frag reads (kk=0,1) + stage-issue + 36 MFMA
        bf16x8 af[2][2], bfr[2][9];
#pragma unroll
        for (int kk = 0; kk < 2; ++kk) {
            const int fslot = ((kk * 4 + lk) ^ rkey) << 4;
#pragma unroll
            for (int mi = 0; mi < 2; ++mi)
                af[kk][mi] = *reinterpret_cast<const bf16x8*>(
                    Ac + (wid * 32 + mi * 16 + lrow) * 128 + fslot);
#pragma unroll
            for (int ni = 0; ni < 9; ++ni)
                bfr[kk][ni] = *reinterpret_cast<const bf16x8*>(
                    Bc + (ni * 16 + lrow) * 128 + fslot);
        }
        if (it < 14) {
            STAGE_A(nb2, (it + 2) * 64);
            if (hasB) STAGE_B(nb2, (it + 2) * 64);
        }
        __builtin_amdgcn_sched_barrier(0);
        asm volatile("s_waitcnt lgkmcnt(0)" ::: "memory");
        __builtin_amdgcn_sched_barrier(0);
        __builtin_amdgcn_s_setprio(1);
#pragma unroll
        for (int kk = 0; kk < 2; ++kk)
#pragma unroll
            for (int ni = 0; ni < 9; ++ni)
#pragma unroll
                for (int mi = 0; mi < 2; ++mi)
                    acc[ni][mi] = __builtin_amdgcn_mfma_f32_16x16x32_bf16(
                        bfr[kk][ni], af[kk][mi], acc[ni][mi], 0, 0, 0);
        __builtin_amdgcn_s_setprio(0);

        cur = (cur + 1 >= 3) ? 0 : cur + 1;
    }
#undef STAGE_A
#undef STAGE_B

    // epilogue: bias + RoPE (in-register pairs) + ushort4 stores
    const float4* bias4 = (const float4*)bias;
#pragma unroll
    for (int ni = 0; ni < 9; ++ni) {
        int cb = n0 + ni * 16 + lk * 4;              // 4 consecutive columns
        float4 bv = bias4[cb >> 2];
        int h = cb >> 7;
        int qki = (cb >> 6) & 1;
        int d0 = cb & 63;                            // multiple of 4
#pragma unroll
        for (int mi = 0; mi < 2; ++mi) {
            int m = m0 + wid * 32 + mi * 16 + lrow;
            int bi = m >> 9, s = m & 511;
            float4 sc = sctab4[s * 16 + (d0 >> 2)];  // {sin j, cos j, sin j+1, cos j+1}
            f32x4 a = acc[ni][mi];
            float v0 = a[0] + bv.x, v1 = a[1] + bv.y;
            float v2 = a[2] + bv.z, v3 = a[3] + bv.w;
            u16x4 p;
            p[0] = f2bf(v0 * sc.y - v1 * sc.x);
            p[1] = f2bf(v1 * sc.y + v0 * sc.x);
            p[2] = f2bf(v2 * sc.w - v3 * sc.z);
            p[3] = f2bf(v3 * sc.w + v2 * sc.z);
            *reinterpret_cast<u16x4*>(
                qk + ((((size_t)bi * HEADS + h) * 2 + qki) * SLEN + s) * HID + d0) = p;
        }
    }
}

// ---------------------------------------------------------------------------
// logits[b,h,m,n] = (q.k * pad - (1-pad)*1e12) / 8
// per (b,h): 512x64 @ 64x512; grid (4,4,144), 128x128 tiles.
// MFMA operand-swapped. LDS-transposed epilogue (R11): per mi-chunk, waves
// write masked f32x4 into a [32][136] f32 tile, then 256 threads store
// contiguous 512B row-chunks (fully coalesced).
// ---------------------------------------------------------------------------
__global__ __launch_bounds__(256) void logits_kernel(
    const unsigned short* __restrict__ qkbuf,  // [16][9][2][512][64] bf16
    const float* __restrict__ mask,            // [16][512]
    float* __restrict__ out)                   // [16][9][512][512]
{
    __shared__ __attribute__((aligned(16))) unsigned short Qs[128 * 72];
    __shared__ __attribute__((aligned(16))) unsigned short Ks[128 * 72];

    const int t = threadIdx.x;
    const int bz = blockIdx.z;                 // b*9 + h
    const int bi = bz / 9;
    const int m0 = blockIdx.x * 128, n0 = blockIdx.y * 128;

    const unsigned short* Qg = qkbuf + ((size_t)bz * 2 + 0) * SLEN * HID + (size_t)m0 * HID;
    const unsigned short* Kg = qkbuf + ((size_t)bz * 2 + 1) * SLEN * HID + (size_t)n0 * HID;

#pragma unroll
    for (int i = 0; i < 4; ++i) {
        int e = t + i * 256;                   // 0..1023
        int row = e >> 3, c = e & 7;           // 8 x 16B per 64-elem row
        *reinterpret_cast<uint4*>(&Qs[row * 72 + c * 8]) =
            *reinterpret_cast<const uint4*>(Qg + (size_t)row * HID + c * 8);
        *reinterpret_cast<uint4*>(&Ks[row * 72 + c * 8]) =
            *reinterpret_cast<const uint4*>(Kg + (size_t)row * HID + c * 8);
    }
    __syncthreads();

    const int wid = t >> 6, lane = t & 63;
    const int wr = wid >> 1, wc = wid & 1;
    const int lrow = lane & 15;
    const int lk = lane >> 4;

    f32x4 acc[4][4] = {};                      // [ni][mi]
#pragma unroll
    for (int kk = 0; kk < 2; ++kk) {
        bf16x8 af[4], bfr[4];
#pragma unroll
        for (int mi = 0; mi < 4; ++mi)
            af[mi] = *reinterpret_cast<const bf16x8*>(
                &Qs[(wr * 64 + mi * 16 + lrow) * 72 + kk * 32 + lk * 8]);
#pragma unroll
        for (int ni = 0; ni < 4; ++ni)
            bfr[ni] = *reinterpret_cast<const bf16x8*>(
                &Ks[(wc * 64 + ni * 16 + lrow) * 72 + kk * 32 + lk * 8]);
#pragma unroll
        for (int ni = 0; ni < 4; ++ni)
#pragma unroll
            for (int mi = 0; mi < 4; ++mi)
                acc[ni][mi] = __builtin_amdgcn_mfma_f32_16x16x32_bf16(
                    bfr[ni], af[mi], acc[ni][mi], 0, 0, 0);
    }

    // mask factors per lane (depend only on n -> ni)
    float4 pv[4]; float4 sub[4];
#pragma unroll
    for (int ni = 0; ni < 4; ++ni) {
        int nb = n0 + wc * 64 + ni * 16 + lk * 4;
        pv[ni] = *reinterpret_cast<const float4*>(mask + bi * SLEN + nb);
        sub[ni].x = (1.0f - pv[ni].x) * 1000000000000.0f;
        sub[ni].y = (1.0f - pv[ni].y) * 1000000000000.0f;
        sub[ni].z = (1.0f - pv[ni].z) * 1000000000000.0f;
        sub[ni].w = (1.0f - pv[ni].w) * 1000000000000.0f;
    }

    // LDS-transposed store: chunk = 32 rows (wr bands) x 128 cols, pad 136
    float* tr = reinterpret_cast<float*>(Qs);   // 32*136*4 = 17408 B < 18432 B
    __syncthreads();                            // all Qs/Ks reads complete
#pragma unroll
    for (int mi = 0; mi < 4; ++mi) {
        if (mi) __syncthreads();                // prev chunk fully stored
#pragma unroll
        for (int ni = 0; ni < 4; ++ni) {
            int col = wc * 64 + ni * 16 + lk * 4;    // 0..127 within tile
            f32x4 a = acc[ni][mi];
            f32x4 o;
            o[0] = (a[0] * pv[ni].x - sub[ni].x) * 0.125f;
            o[1] = (a[1] * pv[ni].y - sub[ni].y) * 0.125f;
            o[2] = (a[2] * pv[ni].z - sub[ni].z) * 0.125f;
            o[3] = (a[3] * pv[ni].w - sub[ni].w) * 0.125f;
            *reinterpret_cast<f32x4*>(&tr[(wr * 16 + lrow) * 136 + col]) = o;
        }
        __syncthreads();
        // store 32 rows x 512B contiguous chunks, fully coalesced
#pragma unroll
        for (int j = 0; j < 4; ++j) {
            int idx = t + j * 256;               // 0..1023
            int r_l = idx >> 5, c4 = idx & 31;   // row 0..31, 16B col 0..31
            int m = m0 + (r_l >> 4) * 64 + mi * 16 + (r_l & 15);
            f32x4 v = *reinterpret_cast<const f32x4*>(&tr[r_l * 136 + c4 * 4]);
            *reinterpret_cast<f32x4*>(
                out + ((size_t)bz * SLEN + m) * SLEN + n0 + c4 * 4) = v;
        }
    }
}

// ---------------------------------------------------------------------------
extern "C" void kernel_launch(void* const* d_in, const int* in_sizes, int n_in,
                              void* d_out, int out_size, void* d_ws, size_t ws_size,
                              hipStream_t stream) {
    const float* hidden = (const float*)d_in[0];   // 16*512*1024
    const float* mask   = (const float*)d_in[1];   // 16*512
    const float* W      = (const float*)d_in[2];   // 1024*1152
    const float* bias   = (const float*)d_in[3];   // 1152
    float* out = (float*)d_out;

    char* ws = (char*)d_ws;
    unsigned short* Ab = (unsigned short*)ws;                        // 16,777,216 B
    unsigned short* Wt = (unsigned short*)(ws + 16777216);           //  2,359,296 B
    float* sctab = (float*)(ws + 16777216 + 2359296);                //    131,072 B
    unsigned short* qk = (unsigned short*)(ws + 16777216 + 2359296 + 131072); // 18,874,368 B

    prep_kernel<<<5312, 256, 0, stream>>>(hidden, W, Ab, Wt, sctab);
    proj_rope_kernel<<<dim3(32, 8), 512, 0, stream>>>(
        Ab, Wt, bias, (const float4*)sctab, qk);
    logits_kernel<<<dim3(4, 4, BATCH * HEADS), 256, 0, stream>>>(qk, mask, out);
}